// Round 5
// baseline (342.124 us; speedup 1.0000x reference)
//
#include <hip/hip_runtime.h>
#include <hip/hip_bf16.h>

#define NU 30000
#define NI 70000
#define NN 100000
#define DD 128
#define NLAYERS 3
#define SLOPE_ 0.01f
#define EPS_ 1e-12f

#define NB 782                 // row buckets of 128 rows
#define NBKT 1024              // padded bucket count (pow2)
#define NBLK 256               // scatter edge segments
#define AROW 136               // LDS A row stride in ushorts (272B = 17*16B)
#define MAXL 32768             // max compacted rows for layer 3
#define BM 64                  // layer kernel M-tile (64 rows/block)

typedef __bf16 v8bf __attribute__((ext_vector_type(8)));
typedef float v16f __attribute__((ext_vector_type(16)));
typedef float v2f __attribute__((ext_vector_type(2)));
typedef unsigned short ushort_t;

union UB8 { uint4 u; v8bf v; };

__device__ __forceinline__ float bflo(unsigned u) { return __uint_as_float(u << 16); }
__device__ __forceinline__ float bfhi(unsigned u) { return __uint_as_float(u & 0xffff0000u); }

__device__ __forceinline__ unsigned pk2(float a, float b) {
    __hip_bfloat162 h = __float22bfloat162_rn(make_float2(a, b));
    return *reinterpret_cast<unsigned*>(&h);
}
__device__ __forceinline__ uint4 pk8(const float* f) {
    return make_uint4(pk2(f[0], f[1]), pk2(f[2], f[3]), pk2(f[4], f[5]), pk2(f[6], f[7]));
}
__device__ __forceinline__ void unp8(uint4 g, float* f) {
    f[0] = bflo(g.x); f[1] = bfhi(g.x);
    f[2] = bflo(g.y); f[3] = bfhi(g.y);
    f[4] = bflo(g.z); f[5] = bfhi(g.z);
    f[6] = bflo(g.w); f[7] = bfhi(g.w);
}
__device__ __forceinline__ ushort_t f2bf1(float x) {
    __hip_bfloat16 h = __float2bfloat16(x);
    return *reinterpret_cast<ushort_t*>(&h);
}

// ---------------------------------------------------------------- concat ----
__global__ __launch_bounds__(256) void k_concat_bf(const float* __restrict__ u,
                                                   const float* __restrict__ it,
                                                   ushort_t* __restrict__ fb) {
    int idx = blockIdx.x * 256 + threadIdx.x;
    if (idx >= NN * DD / 8) return;
    size_t base = (size_t)idx * 8;
    const float* src = (base < (size_t)NU * DD) ? (u + base) : (it + base - (size_t)NU * DD);
    float f[8];
    float4 a = *(const float4*)src;
    float4 b = *(const float4*)(src + 4);
    f[0] = a.x; f[1] = a.y; f[2] = a.z; f[3] = a.w;
    f[4] = b.x; f[5] = b.y; f[6] = b.z; f[7] = b.w;
    *(uint4*)(fb + base) = pk8(f);
}

// ---------------------------------------------------------------- dot -------
__device__ __forceinline__ void dot_body(const ushort_t* __restrict__ fb,
                                         const int* __restrict__ uIdx,
                                         const int* __restrict__ iIdx,
                                         float* __restrict__ out,
                                         int batch, int accum, int blk, int t) {
    int b = blk * 4 + (t >> 6);
    if (b >= batch) return;
    int lane = t & 63;
    unsigned ua = *(const unsigned*)(fb + (size_t)uIdx[b] * DD + lane * 2);
    unsigned ib = *(const unsigned*)(fb + (size_t)(iIdx[b] + NU) * DD + lane * 2);
    float s = bflo(ua) * bflo(ib) + bfhi(ua) * bfhi(ib);
#pragma unroll
    for (int m = 32; m; m >>= 1) s += __shfl_xor(s, m, 64);
    if (lane == 0) out[b] = accum ? out[b] + s : s;
}

__global__ __launch_bounds__(256) void k_dot(const ushort_t* __restrict__ fb,
                                             const int* __restrict__ uIdx,
                                             const int* __restrict__ iIdx,
                                             float* __restrict__ out,
                                             int batch, int accum) {
    dot_body(fb, uIdx, iIdx, out, batch, accum, blockIdx.x, threadIdx.x);
}

// ------------------------------------------------- contention-free CSR build
// pass 1: per-block LDS histograms (1024-thread blocks for occupancy);
// also zeroes layer-3 flags array.
__global__ __launch_bounds__(1024) void k_lhist(const int* __restrict__ rows,
                                                int* __restrict__ ghist,
                                                int* __restrict__ flags,
                                                int nnz, int epb) {
    __shared__ int h[NBKT];
    int t = threadIdx.x, b = blockIdx.x;
    h[t] = 0;
    int i0 = b * 1024 + t;                 // 256*1024 = 262144 >= NN
    if (i0 < NN) flags[i0] = 0;
    __syncthreads();
    int e0 = b * epb, e1 = min(e0 + epb, nnz);
    for (int e = e0 + t; e < e1; e += 1024) atomicAdd(&h[rows[e] >> 7], 1);
    __syncthreads();
    ghist[t * NBLK + b] = h[t];
}

// pass 2a: per-bucket scan of block counts; also sets layer-3 flags + cnt=0.
__global__ __launch_bounds__(256) void k_rscan(int* __restrict__ ghist,
                                               int* __restrict__ btot,
                                               const int* __restrict__ uIdx,
                                               const int* __restrict__ iIdx,
                                               int* __restrict__ flags,
                                               int* __restrict__ cnt, int batch) {
    int t = threadIdx.x;
    int gid = blockIdx.x * 256 + t;          // 0..65535 covers 2*batch=32768
    if (gid == 0) *cnt = 0;
    if (gid < batch) flags[uIdx[gid]] = 1;
    else if (gid < 2 * batch) flags[iIdx[gid - batch] + NU] = 1;

    int bkt = blockIdx.x * 4 + (t >> 6);
    int lane = t & 63;
    int* row = ghist + bkt * NBLK;
    int4 c = *(const int4*)(row + lane * 4);
    int s = c.x + c.y + c.z + c.w;
    int incl = s;
#pragma unroll
    for (int m = 1; m < 64; m <<= 1) {
        int o = __shfl_up(incl, m, 64);
        if (lane >= m) incl += o;
    }
    int excl = incl - s;
    int4 o;
    o.x = excl;
    o.y = o.x + c.x;
    o.z = o.y + c.y;
    o.w = o.z + c.z;
    *(int4*)(row + lane * 4) = o;
    if (lane == 63) btot[bkt] = incl;
}

__global__ __launch_bounds__(256) void k_btscan(const int* __restrict__ btot,
                                                int* __restrict__ bbase) {
    int t = threadIdx.x;
    int4 c = *(const int4*)(btot + t * 4);
    int tsum = c.x + c.y + c.z + c.w;
    int incl = tsum;
#pragma unroll
    for (int m = 1; m < 64; m <<= 1) {
        int o = __shfl_up(incl, m, 64);
        if ((t & 63) >= m) incl += o;
    }
    __shared__ int wsum[4];
    if ((t & 63) == 63) wsum[t >> 6] = incl;
    __syncthreads();
    int off = 0;
    for (int i = 0; i < (t >> 6); ++i) off += wsum[i];
    int excl = off + incl - tsum;
    int4 o;
    o.x = excl;
    o.y = o.x + c.x;
    o.z = o.y + c.y;
    o.w = o.z + c.z;
    *(int4*)(bbase + t * 4) = o;
    if (t == 255) bbase[NBKT] = o.w + c.w;
}

// pass 3: scatter to bucket order (1024-thread blocks); also wave-aggregated
// compaction of flags (one element per thread; grid covers NN).
__global__ __launch_bounds__(1024) void k_sscatter(const int* __restrict__ rows,
                                                   const int* __restrict__ cols,
                                                   const float* __restrict__ vals,
                                                   const int* __restrict__ ghist,
                                                   const int* __restrict__ bbase,
                                                   int2* __restrict__ bedges,
                                                   const int* __restrict__ flags,
                                                   int* __restrict__ list,
                                                   int* __restrict__ cnt,
                                                   int nnz, int epb) {
    __shared__ int base[NBKT];
    __shared__ int h[NBKT];
    int t = threadIdx.x, b = blockIdx.x;
    base[t] = bbase[t] + ghist[t * NBLK + b];
    h[t] = 0;
    // compaction (flags final after k_rscan; cnt zeroed there)
    int lane = t & 63;
    int i = b * 1024 + t;                  // 262144 threads cover NN
    int f = (i < NN) ? flags[i] : 0;
    unsigned long long mask = __ballot(f);
    int total = __popcll(mask);
    int prefix = __popcll(mask & ((1ULL << lane) - 1));
    int bs = 0;
    if (lane == 0 && total) bs = atomicAdd(cnt, total);
    bs = __shfl(bs, 0, 64);
    if (f) list[bs + prefix] = i;
    __syncthreads();
    int e0 = b * epb, e1 = min(e0 + epb, nnz);
    for (int e = e0 + t; e < e1; e += 1024) {
        int r = rows[e];
        int bkt = r >> 7;
        int rank = atomicAdd(&h[bkt], 1);
        bedges[base[bkt] + rank] = make_int2(((r & 127) << 20) | cols[e],
                                             __float_as_int(vals[e]));
    }
}

__global__ __launch_bounds__(256) void k_csort(const int* __restrict__ bbase,
                                               const int2* __restrict__ bedges,
                                               int2* __restrict__ edges,
                                               int* __restrict__ rowPtr, int nnz) {
    __shared__ int cntS[128];
    __shared__ int fillS[128];
    __shared__ int wtot;
    int b = blockIdx.x, t = threadIdx.x;
    int s0 = bbase[b];
    int s1 = bbase[b + 1];
    if (t < 128) cntS[t] = 0;
    __syncthreads();
    for (int i = s0 + t; i < s1; i += 256) atomicAdd(&cntS[bedges[i].x >> 20], 1);
    __syncthreads();
    int v = 0, incl = 0;
    if (t < 128) {
        v = cntS[t];
        incl = v;
#pragma unroll
        for (int m = 1; m < 64; m <<= 1) {
            int o = __shfl_up(incl, m, 64);
            if ((t & 63) >= m) incl += o;
        }
        if (t == 63) wtot = incl;
    }
    __syncthreads();
    if (t < 128) {
        int excl = incl - v + ((t >= 64) ? wtot : 0);
        fillS[t] = excl;
        int gr = b * 128 + t;
        if (gr < NN) rowPtr[gr] = s0 + excl;
    }
    if (b == 0 && t == 0) rowPtr[NN] = nnz;
    __syncthreads();
    for (int i = s0 + t; i < s1; i += 256) {
        int2 e = bedges[i];
        int r = e.x >> 20;
        int p = atomicAdd(&fillS[r], 1);
        edges[s0 + p] = make_int2(e.x & 0xFFFFF, e.y);
    }
}

// ---------------------------------------------------------------- wprep -----
__global__ __launch_bounds__(256) void k_wprep(const float* __restrict__ Wlin,
                                               const float* __restrict__ Wint,
                                               uint4* __restrict__ Wb4) {
    int id = blockIdx.x * 256 + threadIdx.x;   // 0..12287
    int lane = id & 63;
    int w = (id >> 6) & 3;
    int s = (id >> 8) & 7;
    int c = (id >> 11) & 1;
    int l = id >> 12;
    const float* src = (c ? Wint : Wlin) + (size_t)l * DD * DD;
    int n = w * 32 + (lane & 31);
    int k0 = s * 16 + ((lane >> 5) & 1) * 8;
    float f[8];
#pragma unroll
    for (int j = 0; j < 8; ++j) f[j] = src[(size_t)(k0 + j) * DD + n];
    Wb4[id] = pk8(f);
}

// ---------------------------------------------------------------- spmm ------
// quarter-wave (16 lanes) per row; 8-deep gather pipeline: one burst covers
// a full avg-degree row, 32 gathers in flight per wave (2x the 4-deep).
__device__ __forceinline__ void acc_pk(v2f* acc2, uint4 g, float v) {
    v2f vv = {v, v};
    unsigned gw[4] = {g.x, g.y, g.z, g.w};
#pragma unroll
    for (int p = 0; p < 4; ++p) {
        v2f x = {bflo(gw[p]), bfhi(gw[p])};
        acc2[p] = x * vv + acc2[p];
    }
}

__device__ __forceinline__ void spmm_quarter(int r, bool valid, int t,
                                             const int* __restrict__ rowPtr,
                                             const int2* __restrict__ edges,
                                             const ushort_t* __restrict__ fb,
                                             ushort_t* __restrict__ Lxb) {
    int d0 = (t & 15) * 8;
    int beg = 0, end = 0;
    if (valid) { beg = rowPtr[r]; end = rowPtr[r + 1]; }
    v2f acc2[4];
#pragma unroll
    for (int p = 0; p < 4; ++p) acc2[p] = (v2f){0.f, 0.f};
    int e = beg;
    for (; e + 7 < end; e += 8) {
        int2 p[8];
        uint4 g[8];
#pragma unroll
        for (int j = 0; j < 8; ++j) p[j] = edges[e + j];
#pragma unroll
        for (int j = 0; j < 8; ++j)
            g[j] = *(const uint4*)(fb + (size_t)p[j].x * DD + d0);
#pragma unroll
        for (int j = 0; j < 8; ++j) acc_pk(acc2, g[j], __int_as_float(p[j].y));
    }
    if (e + 3 < end) {
        int2 p0 = edges[e];
        int2 p1 = edges[e + 1];
        int2 p2 = edges[e + 2];
        int2 p3 = edges[e + 3];
        uint4 g0 = *(const uint4*)(fb + (size_t)p0.x * DD + d0);
        uint4 g1 = *(const uint4*)(fb + (size_t)p1.x * DD + d0);
        uint4 g2 = *(const uint4*)(fb + (size_t)p2.x * DD + d0);
        uint4 g3 = *(const uint4*)(fb + (size_t)p3.x * DD + d0);
        acc_pk(acc2, g0, __int_as_float(p0.y));
        acc_pk(acc2, g1, __int_as_float(p1.y));
        acc_pk(acc2, g2, __int_as_float(p2.y));
        acc_pk(acc2, g3, __int_as_float(p3.y));
        e += 4;
    }
    if (e + 1 < end) {
        int2 p0 = edges[e];
        int2 p1 = edges[e + 1];
        uint4 g0 = *(const uint4*)(fb + (size_t)p0.x * DD + d0);
        uint4 g1 = *(const uint4*)(fb + (size_t)p1.x * DD + d0);
        acc_pk(acc2, g0, __int_as_float(p0.y));
        acc_pk(acc2, g1, __int_as_float(p1.y));
        e += 2;
    }
    if (e < end) {
        int2 p0 = edges[e];
        uint4 g0 = *(const uint4*)(fb + (size_t)p0.x * DD + d0);
        acc_pk(acc2, g0, __int_as_float(p0.y));
    }
    if (valid) {
        float acc[8];
#pragma unroll
        for (int p = 0; p < 4; ++p) { acc[2 * p] = acc2[p][0]; acc[2 * p + 1] = acc2[p][1]; }
        *(uint4*)(Lxb + (size_t)r * DD + d0) = pk8(acc);
    }
}

// spmm with dot-product blocks prefixed (dot reads same feature buffer)
__global__ __launch_bounds__(256) void k_spmm_dot(const int* __restrict__ rowPtr,
                                                  const int2* __restrict__ edges,
                                                  const ushort_t* __restrict__ fb,
                                                  ushort_t* __restrict__ Lxb,
                                                  const int* __restrict__ uIdx,
                                                  const int* __restrict__ iIdx,
                                                  float* __restrict__ out,
                                                  int batch, int accum, int dotBlocks) {
    if ((int)blockIdx.x < dotBlocks) {
        dot_body(fb, uIdx, iIdx, out, batch, accum, blockIdx.x, threadIdx.x);
        return;
    }
    int ridx = (blockIdx.x - dotBlocks) * 16 + (threadIdx.x >> 4);
    spmm_quarter(ridx, ridx < NN, threadIdx.x, rowPtr, edges, fb, Lxb);
}

__global__ __launch_bounds__(256) void k_spmm_idx_dot(const int* __restrict__ rowPtr,
                                                      const int2* __restrict__ edges,
                                                      const ushort_t* __restrict__ fb,
                                                      ushort_t* __restrict__ Lxb,
                                                      const int* __restrict__ list,
                                                      const int* __restrict__ cnt,
                                                      const int* __restrict__ uIdx,
                                                      const int* __restrict__ iIdx,
                                                      float* __restrict__ out,
                                                      int batch, int dotBlocks) {
    if ((int)blockIdx.x < dotBlocks) {
        dot_body(fb, uIdx, iIdx, out, batch, 1, blockIdx.x, threadIdx.x);
        return;
    }
    int i = (blockIdx.x - dotBlocks) * 16 + (threadIdx.x >> 4);
    bool valid = i < *cnt;
    int r = valid ? list[i] : 0;
    spmm_quarter(r, valid, threadIdx.x, rowPtr, edges, fb, Lxb);
}

// ---------------------------------------------------------------- layer -----
// BM=64 rows/block. Single global pass: load Lxb/fin ONCE, build BOTH the
// (Lx+f) and (Lx*f) LDS tiles, then run both MFMA phases. Halves FETCH vs
// the two-pass version. LDS ~36.4 KB -> 4 blocks/CU at (256,4).
template <bool INDEXED>
__device__ __forceinline__ void layer_body(const ushort_t* __restrict__ Lxb,
                                           const uint4* __restrict__ Wb4,
                                           const float* __restrict__ blin,
                                           const float* __restrict__ bint,
                                           ushort_t* __restrict__ fb,
                                           const ushort_t* __restrict__ fin,
                                           const int* __restrict__ list, int nc) {
    __shared__ ushort_t As[2][BM * AROW];  // 2 x 17408 B
    __shared__ float pnormAll[BM * 4];     // 1024 B
    __shared__ float rinvS[BM];            // 256 B
    __shared__ int rowIdS[BM];             // 256 B

    const int t = threadIdx.x;
    const int w = t >> 6;
    const int l = t & 63;
    const int q = l >> 5;
    const int ln = l & 31;
    const int n = w * 32 + ln;
    const int m0 = blockIdx.x * BM;

    if (INDEXED && m0 >= nc) return;       // whole block empty (uniform)

    if (t < BM) {
        int gi = m0 + t;
        int gm;
        if (INDEXED) gm = (gi < nc) ? list[gi] : -1;
        else gm = (gi < NN) ? gi : -1;
        rowIdS[t] = gm;
    }
    __syncthreads();

    const float bias = blin[n] + bint[n];

    v16f acc[2];
#pragma unroll
    for (int mt = 0; mt < 2; ++mt)
#pragma unroll
        for (int i = 0; i < 16; ++i) acc[mt][i] = 0.f;

    // single-pass fill of both tiles
#pragma unroll
    for (int ii = 0; ii < 4; ++ii) {
        int idx = ii * 256 + t;
        int row = idx >> 4;
        int ch = idx & 15;
        int gm = rowIdS[row];
        uint4 sv = make_uint4(0, 0, 0, 0);
        uint4 pv = make_uint4(0, 0, 0, 0);
        if (gm >= 0) {
            uint4 gl = *(const uint4*)(Lxb + (size_t)gm * DD + ch * 8);
            uint4 gf = *(const uint4*)(fin + (size_t)gm * DD + ch * 8);
            float a[8], b[8], r[8];
            unp8(gl, a);
            unp8(gf, b);
#pragma unroll
            for (int j = 0; j < 8; ++j) r[j] = a[j] + b[j];
            sv = pk8(r);
#pragma unroll
            for (int j = 0; j < 8; ++j) r[j] = a[j] * b[j];
            pv = pk8(r);
        }
        *(uint4*)&As[0][row * AROW + ch * 8] = sv;
        *(uint4*)&As[1][row * AROW + ch * 8] = pv;
    }
    __syncthreads();

#pragma unroll
    for (int c = 0; c < 2; ++c) {
        UB8 bf[8];
#pragma unroll
        for (int s = 0; s < 8; ++s) bf[s].u = Wb4[c * 2048 + s * 256 + w * 64 + l];
#pragma unroll
        for (int mt = 0; mt < 2; ++mt) {
#pragma unroll
            for (int s = 0; s < 8; ++s) {
                v8bf af = *(const v8bf*)&As[c][(mt * 32 + ln) * AROW + s * 16 + q * 8];
                acc[mt] = __builtin_amdgcn_mfma_f32_32x32x16_bf16(af, bf[s].v, acc[mt], 0, 0, 0);
            }
        }
    }

#pragma unroll
    for (int mt = 0; mt < 2; ++mt) {
        float r[16];
#pragma unroll
        for (int reg = 0; reg < 16; ++reg) {
            float v = acc[mt][reg] + bias;
            v = (v > 0.f) ? v : SLOPE_ * v;
            acc[mt][reg] = v;
            r[reg] = v * v;
        }
#pragma unroll
        for (int lev = 0; lev < 4; ++lev) {
            int m = 1 << lev;
            int cnt2 = 8 >> lev;
            bool hi = (l & m) != 0;
#pragma unroll
            for (int i = 0; i < 8; ++i) {
                if (i < cnt2) {
                    float p = hi ? r[2 * i + 1] : r[2 * i];
                    float qv = hi ? r[2 * i] : r[2 * i + 1];
                    r[i] = p + __shfl_xor(qv, m, 64);
                }
            }
        }
        float tot = r[0] + __shfl_xor(r[0], 16, 64);
        if ((l & 31) < 16) {
            int i = l & 15;
            int row = (i & 3) + ((i >> 2) << 3) + 4 * q;
            pnormAll[(mt * 32 + row) * 4 + w] = tot;
        }
    }
    __syncthreads();
    if (t < BM) {
        float4 p = *(const float4*)&pnormAll[t * 4];
        float tot = p.x + p.y + p.z + p.w;
        rinvS[t] = 1.0f / fmaxf(sqrtf(tot), EPS_);
    }
    __syncthreads();

#pragma unroll
    for (int mt = 0; mt < 2; ++mt) {
#pragma unroll
        for (int reg = 0; reg < 16; ++reg) {
            int row = (reg & 3) + ((reg >> 2) << 3) + 4 * q;
            int gm = rowIdS[mt * 32 + row];
            if (gm >= 0)
                fb[(size_t)gm * DD + n] = f2bf1(acc[mt][reg] * rinvS[mt * 32 + row]);
        }
    }
}

__global__ __launch_bounds__(256, 4) void k_layer2(const ushort_t* __restrict__ Lxb,
                                                   const uint4* __restrict__ Wb4,
                                                   const float* __restrict__ blin,
                                                   const float* __restrict__ bint,
                                                   const ushort_t* __restrict__ fin,
                                                   ushort_t* __restrict__ fb) {
    layer_body<false>(Lxb, Wb4, blin, bint, fb, fin, nullptr, 0);
}

__global__ __launch_bounds__(256, 4) void k_layer_idx(const ushort_t* __restrict__ Lxb,
                                                      const uint4* __restrict__ Wb4,
                                                      const float* __restrict__ blin,
                                                      const float* __restrict__ bint,
                                                      const ushort_t* __restrict__ fin,
                                                      ushort_t* __restrict__ fb,
                                                      const int* __restrict__ list,
                                                      const int* __restrict__ cnt) {
    layer_body<true>(Lxb, Wb4, blin, bint, fb, fin, list, *cnt);
}

// ---------------------------------------------------------------- launch ----
extern "C" void kernel_launch(void* const* d_in, const int* in_sizes, int n_in,
                              void* d_out, int out_size, void* d_ws, size_t ws_size,
                              hipStream_t stream) {
    const int*   userIdx = (const int*)d_in[0];
    const int*   itemIdx = (const int*)d_in[1];
    const int*   rows    = (const int*)d_in[2];
    const int*   cols    = (const int*)d_in[3];
    const float* vals    = (const float*)d_in[4];
    const float* uE      = (const float*)d_in[5];
    const float* iE      = (const float*)d_in[6];
    const float* Wlin    = (const float*)d_in[7];
    const float* blin    = (const float*)d_in[8];
    const float* Wint    = (const float*)d_in[9];
    const float* bint    = (const float*)d_in[10];
    float* out = (float*)d_out;

    const int batch = in_sizes[0];
    const int nnz   = in_sizes[2];
    const int epb   = (nnz + NBLK - 1) / NBLK;
    const int dotBlocks = (batch + 3) / 4;

    // ---- workspace layout ----
    ushort_t* featA = (ushort_t*)d_ws;                       // 25.6 MB
    ushort_t* featB = featA + (size_t)NN * DD;               // 25.6 MB (ping-pong)
    ushort_t* Lxb   = featB + (size_t)NN * DD;               // 25.6 MB
    uint4* Wb4      = (uint4*)(Lxb + (size_t)NN * DD);       // 196 KB
    int2*  bedges   = (int2*)(Wb4 + 12288);                  // 8 MB
    int2*  edges    = bedges + nnz;                          // 8 MB
    int*   ghist    = (int*)(edges + nnz);                   // 1 MB
    int*   btot     = ghist + NBKT * NBLK;                   // 4 KB
    int*   bbase    = btot + NBKT;                           // 4 KB (+1)
    int*   rowPtr   = bbase + NBKT + 4;                      // NN+1
    int*   flags    = rowPtr + NN + 4;                       // 400 KB
    int*   list     = flags + NN;                            // 128 KB
    int*   cnt      = list + MAXL;                           // 4 B

    k_concat_bf<<<(NN * DD / 8 + 255) / 256, 256, 0, stream>>>(uE, iE, featA);
    k_wprep<<<48, 256, 0, stream>>>(Wlin, Wint, Wb4);

    // ---- contention-free CSR build (hierarchical scan) + layer-3 row list --
    k_lhist<<<NBLK, 1024, 0, stream>>>(rows, ghist, flags, nnz, epb);
    k_rscan<<<NBKT / 4, 256, 0, stream>>>(ghist, btot, userIdx, itemIdx, flags, cnt, batch);
    k_btscan<<<1, 256, 0, stream>>>(btot, bbase);
    k_sscatter<<<NBLK, 1024, 0, stream>>>(rows, cols, vals, ghist, bbase, bedges,
                                          flags, list, cnt, nnz, epb);
    k_csort<<<NB, 256, 0, stream>>>(bbase, bedges, edges, rowPtr, nnz);

    // layer 1: featA -> featB   (dot-0 on featA fused into spmm grid)
    k_spmm_dot<<<dotBlocks + (NN + 15) / 16, 256, 0, stream>>>(
        rowPtr, edges, featA, Lxb, userIdx, itemIdx, out, batch, 0, dotBlocks);
    k_layer2<<<(NN + BM - 1) / BM, 256, 0, stream>>>(
        Lxb, Wb4, blin, bint, featA, featB);

    // layer 2: featB -> featA   (dot-1 on featB fused)
    k_spmm_dot<<<dotBlocks + (NN + 15) / 16, 256, 0, stream>>>(
        rowPtr, edges, featB, Lxb, userIdx, itemIdx, out, batch, 1, dotBlocks);
    k_layer2<<<(NN + BM - 1) / BM, 256, 0, stream>>>(
        Lxb, Wb4 + 4096, blin + DD, bint + DD, featB, featA);

    // layer 3 (sparse rows): featA -> featB   (dot-2 on featA fused)
    k_spmm_idx_dot<<<dotBlocks + (MAXL + 15) / 16, 256, 0, stream>>>(
        rowPtr, edges, featA, Lxb, list, cnt, userIdx, itemIdx, out, batch, dotBlocks);
    k_layer_idx<<<(MAXL + BM - 1) / BM, 256, 0, stream>>>(
        Lxb, Wb4 + 8192, blin + 2 * DD, bint + 2 * DD, featA, featB, list, cnt);

    // final dot on featB
    k_dot<<<dotBlocks, 256, 0, stream>>>(featB, userIdx, itemIdx, out, batch, 1);
}

// Round 6
// 314.143 us; speedup vs baseline: 1.0891x; 1.0891x over previous
//
#include <hip/hip_runtime.h>
#include <hip/hip_bf16.h>

#define NU 30000
#define NI 70000
#define NN 100000
#define DD 128
#define NLAYERS 3
#define SLOPE_ 0.01f
#define EPS_ 1e-12f

#define NB 782                 // row buckets of 128 rows
#define NBKT 1024              // padded bucket count (pow2)
#define NBLK 256               // scatter edge segments
#define AROW 136               // LDS A row stride in ushorts (272B = 17*16B)
#define MAXL 32768             // max compacted rows for layer 3
#define BM 64                  // layer kernel M-tile (64 rows/block)

typedef __bf16 v8bf __attribute__((ext_vector_type(8)));
typedef float v16f __attribute__((ext_vector_type(16)));
typedef float v2f __attribute__((ext_vector_type(2)));
typedef unsigned short ushort_t;

union UB8 { uint4 u; v8bf v; };

__device__ __forceinline__ float bflo(unsigned u) { return __uint_as_float(u << 16); }
__device__ __forceinline__ float bfhi(unsigned u) { return __uint_as_float(u & 0xffff0000u); }

__device__ __forceinline__ unsigned pk2(float a, float b) {
    __hip_bfloat162 h = __float22bfloat162_rn(make_float2(a, b));
    return *reinterpret_cast<unsigned*>(&h);
}
__device__ __forceinline__ uint4 pk8(const float* f) {
    return make_uint4(pk2(f[0], f[1]), pk2(f[2], f[3]), pk2(f[4], f[5]), pk2(f[6], f[7]));
}
__device__ __forceinline__ void unp8(uint4 g, float* f) {
    f[0] = bflo(g.x); f[1] = bfhi(g.x);
    f[2] = bflo(g.y); f[3] = bfhi(g.y);
    f[4] = bflo(g.z); f[5] = bfhi(g.z);
    f[6] = bflo(g.w); f[7] = bfhi(g.w);
}
__device__ __forceinline__ ushort_t f2bf1(float x) {
    __hip_bfloat16 h = __float2bfloat16(x);
    return *reinterpret_cast<ushort_t*>(&h);
}

// ---------------------------------------------------------------- concat ----
__global__ __launch_bounds__(256) void k_concat_bf(const float* __restrict__ u,
                                                   const float* __restrict__ it,
                                                   ushort_t* __restrict__ fb) {
    int idx = blockIdx.x * 256 + threadIdx.x;
    if (idx >= NN * DD / 8) return;
    size_t base = (size_t)idx * 8;
    const float* src = (base < (size_t)NU * DD) ? (u + base) : (it + base - (size_t)NU * DD);
    float f[8];
    float4 a = *(const float4*)src;
    float4 b = *(const float4*)(src + 4);
    f[0] = a.x; f[1] = a.y; f[2] = a.z; f[3] = a.w;
    f[4] = b.x; f[5] = b.y; f[6] = b.z; f[7] = b.w;
    *(uint4*)(fb + base) = pk8(f);
}

// ---------------------------------------------------------------- dot -------
// one wave handles one batch element b
__device__ __forceinline__ void dot_wave(const ushort_t* __restrict__ fb,
                                         const int* __restrict__ uIdx,
                                         const int* __restrict__ iIdx,
                                         float* __restrict__ out,
                                         int batch, int accum, int b, int lane) {
    if (b >= batch) return;
    unsigned ua = *(const unsigned*)(fb + (size_t)uIdx[b] * DD + lane * 2);
    unsigned ib = *(const unsigned*)(fb + (size_t)(iIdx[b] + NU) * DD + lane * 2);
    float s = bflo(ua) * bflo(ib) + bfhi(ua) * bfhi(ib);
#pragma unroll
    for (int m = 32; m; m >>= 1) s += __shfl_xor(s, m, 64);
    if (lane == 0) out[b] = accum ? out[b] + s : s;
}

__global__ __launch_bounds__(256) void k_dot(const ushort_t* __restrict__ fb,
                                             const int* __restrict__ uIdx,
                                             const int* __restrict__ iIdx,
                                             float* __restrict__ out,
                                             int batch, int accum) {
    dot_wave(fb, uIdx, iIdx, out, batch, accum,
             blockIdx.x * 4 + (threadIdx.x >> 6), threadIdx.x & 63);
}

// ------------------------------------------------- contention-free CSR build
// pass 1: per-block LDS histograms (1024-thread blocks for occupancy);
// also zeroes layer-3 flags array.
__global__ __launch_bounds__(1024) void k_lhist(const int* __restrict__ rows,
                                                int* __restrict__ ghist,
                                                int* __restrict__ flags,
                                                int nnz, int epb) {
    __shared__ int h[NBKT];
    int t = threadIdx.x, b = blockIdx.x;
    h[t] = 0;
    int i0 = b * 1024 + t;                 // 256*1024 = 262144 >= NN
    if (i0 < NN) flags[i0] = 0;
    __syncthreads();
    int e0 = b * epb, e1 = min(e0 + epb, nnz);
    for (int e = e0 + t; e < e1; e += 1024) atomicAdd(&h[rows[e] >> 7], 1);
    __syncthreads();
    ghist[t * NBLK + b] = h[t];
}

// pass 2a: per-bucket scan of block counts; also sets layer-3 flags + cnt=0.
__global__ __launch_bounds__(256) void k_rscan(int* __restrict__ ghist,
                                               int* __restrict__ btot,
                                               const int* __restrict__ uIdx,
                                               const int* __restrict__ iIdx,
                                               int* __restrict__ flags,
                                               int* __restrict__ cnt, int batch) {
    int t = threadIdx.x;
    int gid = blockIdx.x * 256 + t;          // 0..65535 covers 2*batch=32768
    if (gid == 0) *cnt = 0;
    if (gid < batch) flags[uIdx[gid]] = 1;
    else if (gid < 2 * batch) flags[iIdx[gid - batch] + NU] = 1;

    int bkt = blockIdx.x * 4 + (t >> 6);
    int lane = t & 63;
    int* row = ghist + bkt * NBLK;
    int4 c = *(const int4*)(row + lane * 4);
    int s = c.x + c.y + c.z + c.w;
    int incl = s;
#pragma unroll
    for (int m = 1; m < 64; m <<= 1) {
        int o = __shfl_up(incl, m, 64);
        if (lane >= m) incl += o;
    }
    int excl = incl - s;
    int4 o;
    o.x = excl;
    o.y = o.x + c.x;
    o.z = o.y + c.y;
    o.w = o.z + c.z;
    *(int4*)(row + lane * 4) = o;
    if (lane == 63) btot[bkt] = incl;
}

__global__ __launch_bounds__(256) void k_btscan(const int* __restrict__ btot,
                                                int* __restrict__ bbase) {
    int t = threadIdx.x;
    int4 c = *(const int4*)(btot + t * 4);
    int tsum = c.x + c.y + c.z + c.w;
    int incl = tsum;
#pragma unroll
    for (int m = 1; m < 64; m <<= 1) {
        int o = __shfl_up(incl, m, 64);
        if ((t & 63) >= m) incl += o;
    }
    __shared__ int wsum[4];
    if ((t & 63) == 63) wsum[t >> 6] = incl;
    __syncthreads();
    int off = 0;
    for (int i = 0; i < (t >> 6); ++i) off += wsum[i];
    int excl = off + incl - tsum;
    int4 o;
    o.x = excl;
    o.y = o.x + c.x;
    o.z = o.y + c.y;
    o.w = o.z + c.z;
    *(int4*)(bbase + t * 4) = o;
    if (t == 255) bbase[NBKT] = o.w + c.w;
}

// pass 3: scatter to bucket order (1024-thread blocks); also wave-aggregated
// compaction of flags (one element per thread; grid covers NN).
__global__ __launch_bounds__(1024) void k_sscatter(const int* __restrict__ rows,
                                                   const int* __restrict__ cols,
                                                   const float* __restrict__ vals,
                                                   const int* __restrict__ ghist,
                                                   const int* __restrict__ bbase,
                                                   int2* __restrict__ bedges,
                                                   const int* __restrict__ flags,
                                                   int* __restrict__ list,
                                                   int* __restrict__ cnt,
                                                   int nnz, int epb) {
    __shared__ int base[NBKT];
    __shared__ int h[NBKT];
    int t = threadIdx.x, b = blockIdx.x;
    base[t] = bbase[t] + ghist[t * NBLK + b];
    h[t] = 0;
    // compaction (flags final after k_rscan; cnt zeroed there)
    int lane = t & 63;
    int i = b * 1024 + t;                  // 262144 threads cover NN
    int f = (i < NN) ? flags[i] : 0;
    unsigned long long mask = __ballot(f);
    int total = __popcll(mask);
    int prefix = __popcll(mask & ((1ULL << lane) - 1));
    int bs = 0;
    if (lane == 0 && total) bs = atomicAdd(cnt, total);
    bs = __shfl(bs, 0, 64);
    if (f) list[bs + prefix] = i;
    __syncthreads();
    int e0 = b * epb, e1 = min(e0 + epb, nnz);
    for (int e = e0 + t; e < e1; e += 1024) {
        int r = rows[e];
        int bkt = r >> 7;
        int rank = atomicAdd(&h[bkt], 1);
        bedges[base[bkt] + rank] = make_int2(((r & 127) << 20) | cols[e],
                                             __float_as_int(vals[e]));
    }
}

__global__ __launch_bounds__(256) void k_csort(const int* __restrict__ bbase,
                                               const int2* __restrict__ bedges,
                                               int2* __restrict__ edges,
                                               int* __restrict__ rowPtr, int nnz) {
    __shared__ int cntS[128];
    __shared__ int fillS[128];
    __shared__ int wtot;
    int b = blockIdx.x, t = threadIdx.x;
    int s0 = bbase[b];
    int s1 = bbase[b + 1];
    if (t < 128) cntS[t] = 0;
    __syncthreads();
    for (int i = s0 + t; i < s1; i += 256) atomicAdd(&cntS[bedges[i].x >> 20], 1);
    __syncthreads();
    int v = 0, incl = 0;
    if (t < 128) {
        v = cntS[t];
        incl = v;
#pragma unroll
        for (int m = 1; m < 64; m <<= 1) {
            int o = __shfl_up(incl, m, 64);
            if ((t & 63) >= m) incl += o;
        }
        if (t == 63) wtot = incl;
    }
    __syncthreads();
    if (t < 128) {
        int excl = incl - v + ((t >= 64) ? wtot : 0);
        fillS[t] = excl;
        int gr = b * 128 + t;
        if (gr < NN) rowPtr[gr] = s0 + excl;
    }
    if (b == 0 && t == 0) rowPtr[NN] = nnz;
    __syncthreads();
    for (int i = s0 + t; i < s1; i += 256) {
        int2 e = bedges[i];
        int r = e.x >> 20;
        int p = atomicAdd(&fillS[r], 1);
        edges[s0 + p] = make_int2(e.x & 0xFFFFF, e.y);
    }
}

// ---------------------------------------------------------------- wprep -----
__global__ __launch_bounds__(256) void k_wprep(const float* __restrict__ Wlin,
                                               const float* __restrict__ Wint,
                                               uint4* __restrict__ Wb4) {
    int id = blockIdx.x * 256 + threadIdx.x;   // 0..12287
    int lane = id & 63;
    int w = (id >> 6) & 3;
    int s = (id >> 8) & 7;
    int c = (id >> 11) & 1;
    int l = id >> 12;
    const float* src = (c ? Wint : Wlin) + (size_t)l * DD * DD;
    int n = w * 32 + (lane & 31);
    int k0 = s * 16 + ((lane >> 5) & 1) * 8;
    float f[8];
#pragma unroll
    for (int j = 0; j < 8; ++j) f[j] = src[(size_t)(k0 + j) * DD + n];
    Wb4[id] = pk8(f);
}

// -------------------------------------------------------- fused spmm+layer --
// 512-thread block, 64 output rows. Phase 1: quarter-wave-per-row SpMM
// gathers (4-deep pipeline, fp32 accumulate) build the (Lx+f) and (Lx*f)
// LDS tiles directly -- no Lxb global round-trip. Phase 2: 8 waves, one
// 32x32 MFMA acc tile per wave (mt = w>>2 row-half, w2 = w&3 col-group),
// then leaky-relu + row-norm epilogue. __launch_bounds__(512,8): VGPR<=64
// -> 4 blocks/CU (LDS 4x36.4KB) = full 32-wave occupancy in gather phase.
__device__ __forceinline__ void acc_pk(v2f* acc2, uint4 g, float v) {
    v2f vv = {v, v};
    unsigned gw[4] = {g.x, g.y, g.z, g.w};
#pragma unroll
    for (int p = 0; p < 4; ++p) {
        v2f x = {bflo(gw[p]), bfhi(gw[p])};
        acc2[p] = x * vv + acc2[p];
    }
}

template <bool INDEXED>
__device__ __forceinline__ void flayer_body(int bid,
                                            const int* __restrict__ rowPtr,
                                            const int2* __restrict__ edges,
                                            const uint4* __restrict__ Wb4,
                                            const float* __restrict__ blin,
                                            const float* __restrict__ bint,
                                            const ushort_t* __restrict__ fin,
                                            ushort_t* __restrict__ fout,
                                            const int* __restrict__ list, int nc) {
    __shared__ ushort_t As[2][BM * AROW];  // 2 x 17408 B
    __shared__ float pnormAll[BM * 4];     // 1024 B
    __shared__ float rinvS[BM];            // 256 B
    __shared__ int rowIdS[BM];             // 256 B

    const int t = threadIdx.x;             // 0..511
    const int w = t >> 6;                  // wave 0..7
    const int l = t & 63;
    const int mt = w >> 2;                 // row-half 0..1
    const int w2 = w & 3;                  // col-group 0..3
    const int q = l >> 5;
    const int ln = l & 31;
    const int n = w2 * 32 + ln;
    const int m0 = bid * BM;

    if (INDEXED && m0 >= nc) return;       // whole block empty (uniform)

    if (t < BM) {
        int gi = m0 + t;
        int gm;
        if (INDEXED) gm = (gi < nc) ? list[gi] : -1;
        else gm = (gi < NN) ? gi : -1;
        rowIdS[t] = gm;
    }
    __syncthreads();

    // ---- phase 1: SpMM gathers -> sum/product LDS tiles (fp32 Lx) ----
    {
        const int qi = t >> 4;             // quarter 0..31
        const int d0 = (t & 15) * 8;       // 8 channels per lane
#pragma unroll
        for (int j = 0; j < 2; ++j) {
            int row = qi * 2 + j;          // 0..63
            int gm = rowIdS[row];
            uint4 sv = make_uint4(0, 0, 0, 0);
            uint4 pv = make_uint4(0, 0, 0, 0);
            if (gm >= 0) {
                int beg = rowPtr[gm], end = rowPtr[gm + 1];
                v2f acc2[4];
#pragma unroll
                for (int p = 0; p < 4; ++p) acc2[p] = (v2f){0.f, 0.f};
                int e = beg;
                for (; e + 3 < end; e += 4) {
                    int2 p0 = edges[e];
                    int2 p1 = edges[e + 1];
                    int2 p2 = edges[e + 2];
                    int2 p3 = edges[e + 3];
                    uint4 g0 = *(const uint4*)(fin + (size_t)p0.x * DD + d0);
                    uint4 g1 = *(const uint4*)(fin + (size_t)p1.x * DD + d0);
                    uint4 g2 = *(const uint4*)(fin + (size_t)p2.x * DD + d0);
                    uint4 g3 = *(const uint4*)(fin + (size_t)p3.x * DD + d0);
                    acc_pk(acc2, g0, __int_as_float(p0.y));
                    acc_pk(acc2, g1, __int_as_float(p1.y));
                    acc_pk(acc2, g2, __int_as_float(p2.y));
                    acc_pk(acc2, g3, __int_as_float(p3.y));
                }
                if (e + 1 < end) {
                    int2 p0 = edges[e];
                    int2 p1 = edges[e + 1];
                    uint4 g0 = *(const uint4*)(fin + (size_t)p0.x * DD + d0);
                    uint4 g1 = *(const uint4*)(fin + (size_t)p1.x * DD + d0);
                    acc_pk(acc2, g0, __int_as_float(p0.y));
                    acc_pk(acc2, g1, __int_as_float(p1.y));
                    e += 2;
                }
                if (e < end) {
                    int2 p0 = edges[e];
                    uint4 g0 = *(const uint4*)(fin + (size_t)p0.x * DD + d0);
                    acc_pk(acc2, g0, __int_as_float(p0.y));
                }
                float a[8], b8[8], r8[8];
#pragma unroll
                for (int p = 0; p < 4; ++p) {
                    a[2 * p] = acc2[p][0];
                    a[2 * p + 1] = acc2[p][1];
                }
                uint4 gf = *(const uint4*)(fin + (size_t)gm * DD + d0);
                unp8(gf, b8);
#pragma unroll
                for (int k = 0; k < 8; ++k) r8[k] = a[k] + b8[k];
                sv = pk8(r8);
#pragma unroll
                for (int k = 0; k < 8; ++k) r8[k] = a[k] * b8[k];
                pv = pk8(r8);
            }
            *(uint4*)&As[0][row * AROW + d0] = sv;
            *(uint4*)&As[1][row * AROW + d0] = pv;
        }
    }
    __syncthreads();

    // ---- phase 2: MFMA (one 32x32 tile per wave) ----
    const float bias = blin[n] + bint[n];
    v16f acc;
#pragma unroll
    for (int i = 0; i < 16; ++i) acc[i] = 0.f;

#pragma unroll
    for (int c = 0; c < 2; ++c) {
#pragma unroll
        for (int sh = 0; sh < 2; ++sh) {
            UB8 bf[4];
#pragma unroll
            for (int k = 0; k < 4; ++k)
                bf[k].u = Wb4[c * 2048 + (sh * 4 + k) * 256 + w2 * 64 + l];
#pragma unroll
            for (int k = 0; k < 4; ++k) {
                v8bf af = *(const v8bf*)&As[c][(mt * 32 + ln) * AROW + (sh * 4 + k) * 16 + q * 8];
                acc = __builtin_amdgcn_mfma_f32_32x32x16_bf16(af, bf[k].v, acc, 0, 0, 0);
            }
        }
    }

    // ---- epilogue: bias + leaky relu + row-norm ----
    float r[16];
#pragma unroll
    for (int reg = 0; reg < 16; ++reg) {
        float v = acc[reg] + bias;
        v = (v > 0.f) ? v : SLOPE_ * v;
        acc[reg] = v;
        r[reg] = v * v;
    }
#pragma unroll
    for (int lev = 0; lev < 4; ++lev) {
        int m = 1 << lev;
        int cnt2 = 8 >> lev;
        bool hi = (l & m) != 0;
#pragma unroll
        for (int i = 0; i < 8; ++i) {
            if (i < cnt2) {
                float p = hi ? r[2 * i + 1] : r[2 * i];
                float qv = hi ? r[2 * i] : r[2 * i + 1];
                r[i] = p + __shfl_xor(qv, m, 64);
            }
        }
    }
    float tot = r[0] + __shfl_xor(r[0], 16, 64);
    if ((l & 31) < 16) {
        int i = l & 15;
        int row = (i & 3) + ((i >> 2) << 3) + 4 * q;
        pnormAll[(mt * 32 + row) * 4 + w2] = tot;
    }
    __syncthreads();
    if (t < BM) {
        float4 p = *(const float4*)&pnormAll[t * 4];
        float s = p.x + p.y + p.z + p.w;
        rinvS[t] = 1.0f / fmaxf(sqrtf(s), EPS_);
    }
    __syncthreads();

#pragma unroll
    for (int reg = 0; reg < 16; ++reg) {
        int row = (reg & 3) + ((reg >> 2) << 3) + 4 * q;
        int gm = rowIdS[mt * 32 + row];
        if (gm >= 0)
            fout[(size_t)gm * DD + n] = f2bf1(acc[reg] * rinvS[mt * 32 + row]);
    }
}

__global__ __launch_bounds__(512, 8) void k_flayer(const int* __restrict__ rowPtr,
                                                   const int2* __restrict__ edges,
                                                   const uint4* __restrict__ Wb4,
                                                   const float* __restrict__ blin,
                                                   const float* __restrict__ bint,
                                                   const ushort_t* __restrict__ fin,
                                                   ushort_t* __restrict__ fout,
                                                   const int* __restrict__ uIdx,
                                                   const int* __restrict__ iIdx,
                                                   float* __restrict__ out,
                                                   int batch, int accum, int dotBlocks) {
    if ((int)blockIdx.x < dotBlocks) {
        dot_wave(fin, uIdx, iIdx, out, batch, accum,
                 blockIdx.x * 8 + (threadIdx.x >> 6), threadIdx.x & 63);
        return;
    }
    flayer_body<false>(blockIdx.x - dotBlocks, rowPtr, edges, Wb4, blin, bint,
                       fin, fout, nullptr, 0);
}

__global__ __launch_bounds__(512, 8) void k_flayer_idx(const int* __restrict__ rowPtr,
                                                       const int2* __restrict__ edges,
                                                       const uint4* __restrict__ Wb4,
                                                       const float* __restrict__ blin,
                                                       const float* __restrict__ bint,
                                                       const ushort_t* __restrict__ fin,
                                                       ushort_t* __restrict__ fout,
                                                       const int* __restrict__ list,
                                                       const int* __restrict__ cnt,
                                                       const int* __restrict__ uIdx,
                                                       const int* __restrict__ iIdx,
                                                       float* __restrict__ out,
                                                       int batch, int dotBlocks) {
    if ((int)blockIdx.x < dotBlocks) {
        dot_wave(fin, uIdx, iIdx, out, batch, 1,
                 blockIdx.x * 8 + (threadIdx.x >> 6), threadIdx.x & 63);
        return;
    }
    flayer_body<true>(blockIdx.x - dotBlocks, rowPtr, edges, Wb4, blin, bint,
                      fin, fout, list, *cnt);
}

// ---------------------------------------------------------------- launch ----
extern "C" void kernel_launch(void* const* d_in, const int* in_sizes, int n_in,
                              void* d_out, int out_size, void* d_ws, size_t ws_size,
                              hipStream_t stream) {
    const int*   userIdx = (const int*)d_in[0];
    const int*   itemIdx = (const int*)d_in[1];
    const int*   rows    = (const int*)d_in[2];
    const int*   cols    = (const int*)d_in[3];
    const float* vals    = (const float*)d_in[4];
    const float* uE      = (const float*)d_in[5];
    const float* iE      = (const float*)d_in[6];
    const float* Wlin    = (const float*)d_in[7];
    const float* blin    = (const float*)d_in[8];
    const float* Wint    = (const float*)d_in[9];
    const float* bint    = (const float*)d_in[10];
    float* out = (float*)d_out;

    const int batch = in_sizes[0];
    const int nnz   = in_sizes[2];
    const int epb   = (nnz + NBLK - 1) / NBLK;
    const int dotB8 = (batch + 7) / 8;     // fused-layer dot prefix (8 waves/blk)
    const int dotB4 = (batch + 3) / 4;     // standalone final dot

    // ---- workspace layout ----
    ushort_t* featA = (ushort_t*)d_ws;                       // 25.6 MB
    ushort_t* featB = featA + (size_t)NN * DD;               // 25.6 MB (ping-pong)
    uint4* Wb4      = (uint4*)(featB + (size_t)NN * DD);     // 196 KB
    int2*  bedges   = (int2*)(Wb4 + 12288);                  // 8 MB
    int2*  edges    = bedges + nnz;                          // 8 MB
    int*   ghist    = (int*)(edges + nnz);                   // 1 MB
    int*   btot     = ghist + NBKT * NBLK;                   // 4 KB
    int*   bbase    = btot + NBKT;                           // 4 KB (+1)
    int*   rowPtr   = bbase + NBKT + 4;                      // NN+1
    int*   flags    = rowPtr + NN + 4;                       // 400 KB
    int*   list     = flags + NN;                            // 128 KB
    int*   cnt      = list + MAXL;                           // 4 B

    k_concat_bf<<<(NN * DD / 8 + 255) / 256, 256, 0, stream>>>(uE, iE, featA);
    k_wprep<<<48, 256, 0, stream>>>(Wlin, Wint, Wb4);

    // ---- contention-free CSR build (hierarchical scan) + layer-3 row list --
    k_lhist<<<NBLK, 1024, 0, stream>>>(rows, ghist, flags, nnz, epb);
    k_rscan<<<NBKT / 4, 256, 0, stream>>>(ghist, btot, userIdx, itemIdx, flags, cnt, batch);
    k_btscan<<<1, 256, 0, stream>>>(btot, bbase);
    k_sscatter<<<NBLK, 1024, 0, stream>>>(rows, cols, vals, ghist, bbase, bedges,
                                          flags, list, cnt, nnz, epb);
    k_csort<<<NB, 256, 0, stream>>>(bbase, bedges, edges, rowPtr, nnz);

    // layer 1 (fused spmm+layer, dot-0 prefix): featA -> featB
    k_flayer<<<dotB8 + (NN + BM - 1) / BM, 512, 0, stream>>>(
        rowPtr, edges, Wb4, blin, bint, featA, featB,
        userIdx, itemIdx, out, batch, 0, dotB8);

    // layer 2 (dot-1 prefix): featB -> featA
    k_flayer<<<dotB8 + (NN + BM - 1) / BM, 512, 0, stream>>>(
        rowPtr, edges, Wb4 + 4096, blin + DD, bint + DD, featB, featA,
        userIdx, itemIdx, out, batch, 1, dotB8);

    // layer 3 (sparse rows, dot-2 prefix): featA -> featB
    k_flayer_idx<<<dotB8 + (MAXL + BM - 1) / BM, 512, 0, stream>>>(
        rowPtr, edges, Wb4 + 8192, blin + 2 * DD, bint + 2 * DD, featA, featB,
        list, cnt, userIdx, itemIdx, out, batch, dotB8);

    // final dot on featB
    k_dot<<<dotB4, 256, 0, stream>>>(featB, userIdx, itemIdx, out, batch, 1);
}